// Round 2
// baseline (830.831 us; speedup 1.0000x reference)
//
#include <hip/hip_runtime.h>
#include <stdint.h>

#define N_NODES 20000
#define E_EDGES 160000
#define C_DIM 32
#define F_DIM 65          // 2C + NEF
#define EF_STRIDE 66
#define OUT_DIM 128
#define NSLOT 14          // NUM_ANGLE*2
#define K_REAL 910        // NSLOT*F_DIM
#define KP 960            // padded K (15 * 64)
#define BK 64
#define MT 128

typedef __attribute__((ext_vector_type(4))) float f32x4;
typedef __attribute__((ext_vector_type(8))) short short8;

__device__ __forceinline__ float bf2f(unsigned short u){
  union { unsigned int i; float f; } v; v.i = ((unsigned int)u) << 16; return v.f;
}
__device__ __forceinline__ unsigned short f2bf(float f){
  union { float f; unsigned int i; } v; v.f = f;
  unsigned int i = v.i;
  unsigned int r = (i + 0x7FFFu + ((i >> 16) & 1u)) >> 16;
  return (unsigned short)r;
}
// flag-dispatched float load: isbf=1 -> bf16 ushort, else fp32
__device__ __forceinline__ float ldv(const void* p, size_t i, int isbf){
  return isbf ? bf2f(((const unsigned short*)p)[i]) : ((const float*)p)[i];
}

// ---------------- dtype sniffer ----------------
// If x is fp32, its even ushorts are mantissa garbage -> huge/NaN bf16 values.
__global__ void k_sniff(const void* xraw, int* flag){
  const unsigned short* xu = (const unsigned short*)xraw;
  __shared__ int s_bad;
  int tid = threadIdx.x;
  if (tid == 0) s_bad = 0;
  __syncthreads();
  int idx = tid * 2499;              // < 640000 for tid<256; parity alternates
  float v = bf2f(xu[idx]);
  if (!(fabsf(v) < 100.0f)) s_bad = 1;   // NaN also lands here
  __syncthreads();
  if (tid == 0) flag[0] = s_bad ? 0 : 1; // 1 = bf16, 0 = fp32
}

// ---------------- zero ----------------
__global__ void k_zero(int* p, int n){
  int i = blockIdx.x*blockDim.x + threadIdx.x;
  if (i < n) p[i] = 0;
}

// ---------------- build edge features, edge vectors, degree histograms ----------------
__global__ void k_build(const void* __restrict__ x,
                        const void* __restrict__ eattr,
                        const void* __restrict__ pos,
                        const int* __restrict__ row, const int* __restrict__ col,
                        unsigned short* __restrict__ edge_f,
                        float* __restrict__ vecn,
                        int* __restrict__ cnt_row, int* __restrict__ cnt_col,
                        const int* __restrict__ flg)
{
  int isbf = flg[0];
  int tid = threadIdx.x;
  int le = tid >> 5, t = tid & 31;
  int e = blockIdx.x*8 + le;
  if (e >= E_EDGES) return;
  int r = row[e], c = col[e];
  edge_f[e*EF_STRIDE + t]         = f2bf(ldv(x, (size_t)r*C_DIM + t, isbf));
  edge_f[e*EF_STRIDE + C_DIM + t] = f2bf(ldv(x, (size_t)c*C_DIM + t, isbf));
  if (t == 0){
    edge_f[e*EF_STRIDE + 64] = f2bf(ldv(eattr, e, isbf));
    edge_f[e*EF_STRIDE + 65] = 0;
    float vx = ldv(pos, (size_t)c*3+0, isbf) - ldv(pos, (size_t)r*3+0, isbf);
    float vy = ldv(pos, (size_t)c*3+1, isbf) - ldv(pos, (size_t)r*3+1, isbf);
    float vz = ldv(pos, (size_t)c*3+2, isbf) - ldv(pos, (size_t)r*3+2, isbf);
    float nn = sqrtf(vx*vx + vy*vy + vz*vz);
    vecn[e*4+0] = vx; vecn[e*4+1] = vy; vecn[e*4+2] = vz; vecn[e*4+3] = nn;
    atomicAdd(cnt_row + r, 1);
    atomicAdd(cnt_col + c, 1);
  }
}

// ---------------- exclusive scan of degree histograms (2 blocks: row / col) ----------------
__global__ void k_scan(const int* __restrict__ cnt_row, int* start_row, int* fill_row,
                       const int* __restrict__ cnt_col, int* start_col, int* fill_col)
{
  const int* cnt = blockIdx.x ? cnt_col : cnt_row;
  int* start = blockIdx.x ? start_col : start_row;
  int* fill  = blockIdx.x ? fill_col  : fill_row;
  __shared__ int buf[1024];
  __shared__ int carry_s;
  int tid = threadIdx.x;
  if (tid == 0) carry_s = 0;
  __syncthreads();
  for (int base = 0; base < N_NODES; base += 1024){
    int i = base + tid;
    int v = (i < N_NODES) ? cnt[i] : 0;
    buf[tid] = v;
    __syncthreads();
    #pragma unroll
    for (int off = 1; off < 1024; off <<= 1){
      int tsum = (tid >= off) ? buf[tid - off] : 0;
      __syncthreads();
      buf[tid] += tsum;
      __syncthreads();
    }
    int carry = carry_s;
    int excl = carry + buf[tid] - v;
    if (i < N_NODES){ start[i] = excl; fill[i] = excl; }
    int tot = buf[1023];
    __syncthreads();
    if (tid == 0) carry_s = carry + tot;
    __syncthreads();
  }
  if (tid == 0) start[N_NODES] = carry_s;
}

// ---------------- scatter edge ids into CSR lists ----------------
__global__ void k_scatter(const int* __restrict__ row, const int* __restrict__ col,
                          int* fill_row, int* fill_col,
                          int* list_row, int* list_col)
{
  int e = blockIdx.x*blockDim.x + threadIdx.x;
  if (e >= E_EDGES) return;
  int p = atomicAdd(fill_row + row[e], 1); list_row[p] = e;
  int q = atomicAdd(fill_col + col[e], 1); list_col[q] = e;
}

// ---------------- pack W into padded [128][KP] bf16 ----------------
__global__ void k_packw(const void* __restrict__ W, unsigned short* __restrict__ Wp,
                        const int* __restrict__ flg){
  int isbf = flg[0];
  int i = blockIdx.x*blockDim.x + threadIdx.x;
  if (i >= OUT_DIM*KP) return;
  int o = i / KP, k = i - o*KP;
  Wp[i] = (k < K_REAL) ? f2bf(ldv(W, (size_t)o*K_REAL + k, isbf)) : (unsigned short)0;
}

// ---------------- per-edge message accumulation (one wave per edge) ----------------
__global__ __launch_bounds__(256)
void k_msg(const unsigned short* __restrict__ edge_f,
           const float* __restrict__ vecn,
           const int* __restrict__ row, const int* __restrict__ col,
           const int* __restrict__ start_row, const int* __restrict__ list_row,
           const int* __restrict__ start_col, const int* __restrict__ list_col,
           unsigned short* __restrict__ msg, int e0, int ce)
{
  __shared__ float accs[4][NSLOT*EF_STRIDE];
  int tid = threadIdx.x;
  int wv = tid >> 6, lane = tid & 63;
  int el = blockIdx.x*4 + wv;
  if (el >= ce) return;
  int e = e0 + el;
  float* ac = accs[wv];
  for (int i = lane; i < NSLOT*EF_STRIDE; i += 64) ac[i] = 0.f;

  float vex = vecn[e*4+0], vey = vecn[e*4+1], vez = vecn[e*4+2], ven = vecn[e*4+3];
  const float cb1 = 0.9009688679f, cb2 = 0.6234898019f, cb3 = 0.2225209340f;

  // incoming: a with col[a] == row[e]  -> slot 2t (features of a)
  int j = row[e];
  int lo = start_col[j], hi = start_col[j+1];
  for (int it = lo; it < hi; ++it){
    int a = list_col[it];
    float ax = vecn[a*4+0], ay = vecn[a*4+1], az = vecn[a*4+2], an = vecn[a*4+3];
    float cosv = -(ax*vex + ay*vey + az*vez) / (an*ven + 1e-8f);
    int tb = (cosv<=cb1)+(cosv<=cb2)+(cosv<=cb3)+(cosv<=-cb3)+(cosv<=-cb2)+(cosv<=-cb1);
    float* dst = ac + (2*tb)*EF_STRIDE;
    const unsigned short* src = edge_f + (size_t)a*EF_STRIDE;
    for (int f = lane; f < F_DIM; f += 64) dst[f] += bf2f(src[f]);
  }
  // outgoing: b with row[b] == col[e]  -> slot 2t+1 (features of b)
  int j2 = col[e];
  lo = start_row[j2]; hi = start_row[j2+1];
  for (int it = lo; it < hi; ++it){
    int b = list_row[it];
    float bx = vecn[b*4+0], by = vecn[b*4+1], bz = vecn[b*4+2], bn = vecn[b*4+3];
    float cosv = -(bx*vex + by*vey + bz*vez) / (bn*ven + 1e-8f);
    int tb = (cosv<=cb1)+(cosv<=cb2)+(cosv<=cb3)+(cosv<=-cb3)+(cosv<=-cb2)+(cosv<=-cb1);
    float* dst = ac + (2*tb+1)*EF_STRIDE;
    const unsigned short* src = edge_f + (size_t)b*EF_STRIDE;
    for (int f = lane; f < F_DIM; f += 64) dst[f] += bf2f(src[f]);
  }
  // write bf16 msg row, zero-padded to KP
  unsigned short* outp = msg + (size_t)el*KP;
  for (int idx = lane; idx < KP; idx += 64){
    float v = 0.f;
    if (idx < K_REAL){ int slot = idx / F_DIM; int f = idx - slot*F_DIM; v = ac[slot*EF_STRIDE + f]; }
    outp[idx] = f2bf(v);
  }
}

// ---------------- GEMM: per-edge hidden = msg @ Wp^T + b ----------------
// use_hidden=1: write hidden[E][128];  use_hidden=0: atomicAdd into node_acc[col[e]][o]
__global__ __launch_bounds__(256)
void k_gemm(const unsigned short* __restrict__ msg,
            const unsigned short* __restrict__ Wp,
            const void* __restrict__ bias,
            const int* __restrict__ flg,
            const int* __restrict__ colp,
            float* __restrict__ node_acc,
            float* __restrict__ hidden,
            int use_hidden, int e0, int ce)
{
  __shared__ unsigned short As[MT*BK];
  __shared__ unsigned short Bs[OUT_DIM*BK];
  int tid = threadIdx.x;
  int w = tid >> 6, lane = tid & 63;
  int lrow = lane & 15, q = lane >> 4;
  int m0 = blockIdx.x * MT;

  f32x4 acc[2][8];
  #pragma unroll
  for (int i = 0; i < 2; ++i)
    #pragma unroll
    for (int jn = 0; jn < 8; ++jn) acc[i][jn] = (f32x4)0.f;

  for (int k0 = 0; k0 < KP; k0 += BK){
    __syncthreads();
    #pragma unroll
    for (int i = 0; i < 4; ++i){
      int idx = tid + i*256;           // 1024 16B chunks each for A and B
      int rr = idx >> 3, cc = idx & 7;
      int gm = m0 + rr; if (gm >= ce) gm = ce - 1;
      const uint4* gp = (const uint4*)(msg + (size_t)gm*KP + k0 + cc*8);
      *(uint4*)(As + rr*BK + ((cc ^ (rr & 7)) * 8)) = *gp;
      const uint4* gq = (const uint4*)(Wp + (size_t)rr*KP + k0 + cc*8);
      *(uint4*)(Bs + rr*BK + ((cc ^ (rr & 7)) * 8)) = *gq;
    }
    __syncthreads();
    #pragma unroll
    for (int kk = 0; kk < 2; ++kk){
      int cbase = kk*4 + q;
      int ra0 = w*32 + lrow;
      int ra1 = ra0 + 16;
      short8 a0 = *(const short8*)(As + ra0*BK + ((cbase ^ (ra0 & 7))*8));
      short8 a1 = *(const short8*)(As + ra1*BK + ((cbase ^ (ra1 & 7))*8));
      #pragma unroll
      for (int nf = 0; nf < 8; ++nf){
        int rb = nf*16 + lrow;
        short8 bfr = *(const short8*)(Bs + rb*BK + ((cbase ^ (rb & 7))*8));
        acc[0][nf] = __builtin_amdgcn_mfma_f32_16x16x32_bf16(a0, bfr, acc[0][nf], 0, 0, 0);
        acc[1][nf] = __builtin_amdgcn_mfma_f32_16x16x32_bf16(a1, bfr, acc[1][nf], 0, 0, 0);
      }
    }
  }
  int isbf = flg[0];
  float bvs[8];
  #pragma unroll
  for (int nf = 0; nf < 8; ++nf) bvs[nf] = ldv(bias, nf*16 + lrow, isbf);

  #pragma unroll
  for (int mf = 0; mf < 2; ++mf){
    #pragma unroll
    for (int r = 0; r < 4; ++r){
      int m = w*32 + mf*16 + q*4 + r;
      if (m0 + m >= ce) continue;
      int eg = e0 + m0 + m;
      if (use_hidden){
        #pragma unroll
        for (int nf = 0; nf < 8; ++nf)
          hidden[(size_t)eg*OUT_DIM + nf*16 + lrow] = acc[mf][nf][r] + bvs[nf];
      } else {
        int cv = colp[eg];
        #pragma unroll
        for (int nf = 0; nf < 8; ++nf)
          atomicAdd(node_acc + (size_t)cv*OUT_DIM + nf*16 + lrow, acc[mf][nf][r] + bvs[nf]);
      }
    }
  }
}

// ---------------- node gather (hidden path): node_acc[n] = sum hidden over incoming ----------------
__global__ void k_gather(const float* __restrict__ hidden,
                         const int* __restrict__ start_col, const int* __restrict__ list_col,
                         float* __restrict__ node_acc)
{
  int n = blockIdx.x;
  int o = threadIdx.x;
  int lo = start_col[n], hi = start_col[n+1];
  float s = 0.f;
  for (int i = lo; i < hi; ++i){
    int e = list_col[i];
    s += hidden[(size_t)e*OUT_DIM + o];
  }
  node_acc[(size_t)n*OUT_DIM + o] = s;
}

// ---------------- convert node_acc -> d_out per flag ----------------
__global__ void k_out(const float* __restrict__ acc, void* outp, const int* __restrict__ flg){
  int i = blockIdx.x*blockDim.x + threadIdx.x;
  if (i >= N_NODES*OUT_DIM) return;
  if (flg[0]) ((unsigned short*)outp)[i] = f2bf(acc[i]);
  else        ((float*)outp)[i] = acc[i];
}

extern "C" void kernel_launch(void* const* d_in, const int* in_sizes, int n_in,
                              void* d_out, int out_size, void* d_ws, size_t ws_size,
                              hipStream_t stream)
{
  const void* x     = d_in[0];
  const void* eattr = d_in[1];
  const void* pos   = d_in[2];
  const void* W     = d_in[3];
  const void* bmsg  = d_in[4];
  const int* eidx = (const int*)d_in[5];
  const int* row = eidx;
  const int* col = eidx + E_EDGES;

  char* ws = (char*)d_ws;
  size_t off = 0;
  auto alloc = [&](size_t b){ size_t o = off; off += (b + 255) & ~(size_t)255; return o; };

  int* dflag       = (int*)(ws + alloc(256));
  unsigned short* edge_f = (unsigned short*)(ws + alloc((size_t)E_EDGES*EF_STRIDE*2));
  float* vecn      = (float*)(ws + alloc((size_t)E_EDGES*16));
  int* cnt_row     = (int*)(ws + alloc((size_t)N_NODES*4));
  int* cnt_col     = (int*)(ws + alloc((size_t)N_NODES*4));
  int* start_row   = (int*)(ws + alloc((size_t)(N_NODES+1)*4));
  int* start_col   = (int*)(ws + alloc((size_t)(N_NODES+1)*4));
  int* fill_row    = (int*)(ws + alloc((size_t)N_NODES*4));
  int* fill_col    = (int*)(ws + alloc((size_t)N_NODES*4));
  int* list_row    = (int*)(ws + alloc((size_t)E_EDGES*4));
  int* list_col    = (int*)(ws + alloc((size_t)E_EDGES*4));
  unsigned short* Wp = (unsigned short*)(ws + alloc((size_t)OUT_DIM*KP*2));
  float* node_acc  = (float*)(ws + alloc((size_t)N_NODES*OUT_DIM*4));

  // optional hidden buffer (atomic-free path) if workspace affords it
  size_t need_hidden = (size_t)E_EDGES*OUT_DIM*4;
  size_t msg_min = (size_t)MT*KP*2;
  int use_hidden = (ws_size > off + need_hidden + msg_min + 4096) ? 1 : 0;
  float* hidden = node_acc; // dummy alias when unused
  if (use_hidden) hidden = (float*)(ws + alloc(need_hidden));

  size_t remain = (ws_size > off) ? (ws_size - off) : 0;
  long long chunk = (long long)(remain / ((size_t)KP*2));
  if (chunk > E_EDGES) chunk = E_EDGES;
  chunk &= ~(long long)127;          // multiple of MT
  if (chunk < 128) chunk = 128;      // minimal fallback
  unsigned short* msg = (unsigned short*)(ws + off);

  k_sniff<<<1, 256, 0, stream>>>(x, dflag);
  k_zero<<<(N_NODES+255)/256, 256, 0, stream>>>(cnt_row, N_NODES);
  k_zero<<<(N_NODES+255)/256, 256, 0, stream>>>(cnt_col, N_NODES);
  k_zero<<<(N_NODES*OUT_DIM+255)/256, 256, 0, stream>>>((int*)node_acc, N_NODES*OUT_DIM);
  k_build<<<E_EDGES/8, 256, 0, stream>>>(x, eattr, pos, row, col, edge_f, vecn, cnt_row, cnt_col, dflag);
  k_scan<<<2, 1024, 0, stream>>>(cnt_row, start_row, fill_row, cnt_col, start_col, fill_col);
  k_scatter<<<(E_EDGES+255)/256, 256, 0, stream>>>(row, col, fill_row, fill_col, list_row, list_col);
  k_packw<<<(OUT_DIM*KP+255)/256, 256, 0, stream>>>(W, Wp, dflag);

  for (long long e0 = 0; e0 < E_EDGES; e0 += chunk){
    int ce = (int)(((long long)E_EDGES - e0) < chunk ? ((long long)E_EDGES - e0) : chunk);
    k_msg<<<(ce+3)/4, 256, 0, stream>>>(edge_f, vecn, row, col,
                                        start_row, list_row, start_col, list_col,
                                        msg, (int)e0, ce);
    k_gemm<<<(ce+127)/128, 256, 0, stream>>>(msg, Wp, bmsg, dflag, col,
                                             node_acc, hidden, use_hidden, (int)e0, ce);
  }
  if (use_hidden)
    k_gather<<<N_NODES, OUT_DIM, 0, stream>>>(hidden, start_col, list_col, node_acc);
  k_out<<<(N_NODES*OUT_DIM+255)/256, 256, 0, stream>>>(node_acc, d_out, dflag);
}

// Round 5
// 435.171 us; speedup vs baseline: 1.9092x; 1.9092x over previous
//
#include <hip/hip_runtime.h>
#include <stdint.h>

#define N_NODES 20000
#define E_EDGES 160000
#define C_DIM 32
#define OUT_DIM 128
#define K_REAL 910
#define KPH 512           // padded per-half K (455 real + 57 zeros)
#define BK 64
#define MT 128
#define DEG_CAP 64
#define SEG 1024
#define NSEG 20           // ceil(20000/1024)

typedef __attribute__((ext_vector_type(4))) float f32x4;
typedef __attribute__((ext_vector_type(8))) short short8;

__device__ __forceinline__ float bf2f(unsigned short u){
  union { unsigned int i; float f; } v; v.i = ((unsigned int)u) << 16; return v.f;
}
__device__ __forceinline__ unsigned short f2bf(float f){
  union { float f; unsigned int i; } v; v.f = f;
  unsigned int i = v.i;
  unsigned int r = (i + 0x7FFFu + ((i >> 16) & 1u)) >> 16;
  return (unsigned short)r;
}
__device__ __forceinline__ float ldv(const void* p, size_t i, int isbf){
  return isbf ? bf2f(((const unsigned short*)p)[i]) : ((const float*)p)[i];
}
__device__ __forceinline__ int clampi(int v, int hi){  // [0, hi)
  return ((unsigned)v < (unsigned)hi) ? v : 0;
}

// ---------------- dtype sniffer ----------------
__global__ void k_sniff(const void* xraw, int* flag){
  const unsigned short* xu = (const unsigned short*)xraw;
  __shared__ int s_bad;
  int tid = threadIdx.x;
  if (tid == 0) s_bad = 0;
  __syncthreads();
  float v = bf2f(xu[tid * 2499]);
  if (!(fabsf(v) < 100.0f)) s_bad = 1;
  __syncthreads();
  if (tid == 0) flag[0] = s_bad ? 0 : 1; // 1 = bf16, 0 = fp32
}

__global__ void k_zero(int* p, int n){
  int i = blockIdx.x*blockDim.x + threadIdx.x;
  if (i < n) p[i] = 0;
}

// ---------------- edge vectors + degree histograms ----------------
__global__ void k_build(const void* __restrict__ pos,
                        const int* __restrict__ row, const int* __restrict__ col,
                        float* __restrict__ vecn, int* __restrict__ cnt,
                        const int* __restrict__ flg)
{
  int e = blockIdx.x*blockDim.x + threadIdx.x;
  if (e >= E_EDGES) return;
  int isbf = flg[0];
  int r = clampi(row[e], N_NODES), c = clampi(col[e], N_NODES);
  float vx = ldv(pos, (size_t)c*3+0, isbf) - ldv(pos, (size_t)r*3+0, isbf);
  float vy = ldv(pos, (size_t)c*3+1, isbf) - ldv(pos, (size_t)r*3+1, isbf);
  float vz = ldv(pos, (size_t)c*3+2, isbf) - ldv(pos, (size_t)r*3+2, isbf);
  float nn = sqrtf(vx*vx + vy*vy + vz*vz);
  f32x4 vv; vv[0]=vx; vv[1]=vy; vv[2]=vz; vv[3]=nn;
  *(f32x4*)(vecn + (size_t)e*4) = vv;
  atomicAdd(cnt + r, 1);
  atomicAdd(cnt + N_NODES + c, 1);
}

// ---------------- 3-phase exclusive scan over cnt[2N] ----------------
__global__ void k_scan1(const int* __restrict__ cnt, int* __restrict__ start2,
                        int* __restrict__ segsum){
  __shared__ int buf[SEG];
  int b = blockIdx.x, arr = b / NSEG, seg = b - arr*NSEG;
  const int* cntp = cnt + (size_t)arr*N_NODES;
  int* startp = start2 + (size_t)arr*(N_NODES+1);
  int tid = threadIdx.x;
  int i = seg*SEG + tid;
  int v = (i < N_NODES) ? cntp[i] : 0;
  buf[tid] = v;
  __syncthreads();
  for (int off = 1; off < SEG; off <<= 1){
    int t = (tid >= off) ? buf[tid-off] : 0;
    __syncthreads();
    buf[tid] += t;
    __syncthreads();
  }
  if (i < N_NODES) startp[i] = buf[tid] - v;
  if (tid == SEG-1) segsum[b] = buf[tid];
}
__global__ void k_scan2(int* segsum){
  int tid = threadIdx.x;
  if (tid < 2){
    int run = 0;
    for (int s = 0; s < NSEG; ++s){
      int v = segsum[tid*NSEG+s]; segsum[tid*NSEG+s] = run; run += v;
    }
  }
}
__global__ void k_scan3(int* __restrict__ start2, int* __restrict__ fill2,
                        const int* __restrict__ segsum){
  int b = blockIdx.x, arr = b / NSEG, seg = b - arr*NSEG;
  int* startp = start2 + (size_t)arr*(N_NODES+1);
  int* fillp  = fill2  + (size_t)arr*N_NODES;
  int tid = threadIdx.x;
  int i = seg*SEG + tid;
  int add = segsum[b];
  if (i < N_NODES){ int s = startp[i] + add; startp[i] = s; fillp[i] = s; }
  if (b == 0 && tid == 0){
    start2[N_NODES] = E_EDGES;
    start2[(N_NODES+1) + N_NODES] = E_EDGES;
  }
}

// ---------------- scatter edge ids into CSR lists (+ inverse col perm) ----------------
__global__ void k_scatter(const int* __restrict__ row, const int* __restrict__ col,
                          int* fill2, int* list_row, int* list_col, int* pos_col)
{
  int e = blockIdx.x*blockDim.x + threadIdx.x;
  if (e >= E_EDGES) return;
  int r = clampi(row[e], N_NODES), c = clampi(col[e], N_NODES);
  int p = atomicAdd(fill2 + r, 1);
  if ((unsigned)p < E_EDGES) list_row[p] = e;
  int q = atomicAdd(fill2 + N_NODES + c, 1);
  if ((unsigned)q < E_EDGES) list_col[q] = e;
  pos_col[e] = clampi(q, E_EDGES);
}

// ---------------- pack W into two padded halves Wp[half][128][KPH] ----------------
// W col for (slot t, half h, feat f) = (2t+h)*65 + f
__global__ void k_packw(const void* __restrict__ W, unsigned short* __restrict__ Wp,
                        const int* __restrict__ flg){
  int isbf = flg[0];
  int i = blockIdx.x*blockDim.x + threadIdx.x;
  if (i >= 2*OUT_DIM*KPH) return;
  int half = i / (OUT_DIM*KPH);
  int rem = i - half*OUT_DIM*KPH;
  int o = rem / KPH, kp = rem - o*KPH;
  float v = 0.f;
  if (kp < 455){
    int t = kp/65, f = kp - t*65;
    v = ldv(W, (size_t)o*K_REAL + (2*t + half)*65 + f, isbf);
  }
  Wp[i] = f2bf(v);
}

// ---------------- node-centric message build, one half per pass ----------------
// half=0 (in):  sources = I(j)={a: col[a]=j}, targets = O(j)={b: row[b]=j};
//               edge b's in-half written once by node row[b].
// half=1 (out): sources = O(j), targets = I(j); edge a's out-half by node col[a].
// Row layout: k = t*65 + f (t=bin, f<64 node-feats, f=64 eattr), zeros [455,512).
__global__ __launch_bounds__(256)
void k_msg_node(const void* __restrict__ x, const void* __restrict__ eattr,
                const float* __restrict__ vecn,
                const int* __restrict__ row, const int* __restrict__ col,
                const int* __restrict__ start2,
                const int* __restrict__ list_row, const int* __restrict__ list_col,
                const int* __restrict__ pos_col,
                unsigned short* __restrict__ msg,
                const int* __restrict__ flg, int half)
{
  __shared__ int posT[DEG_CAP];
  __shared__ int othS[DEG_CAP];
  __shared__ float vS[DEG_CAP][4], vT[DEG_CAP][4];
  __shared__ float eS[DEG_CAP];
  __shared__ unsigned short fS[DEG_CAP][64];
  __shared__ float e64[DEG_CAP][8];
  __shared__ unsigned char bins[DEG_CAP][DEG_CAP]; // [target][source]

  const float cb1 = 0.9009688679f, cb2 = 0.6234898019f, cb3 = 0.2225209340f;
  const int* start_row = start2;
  const int* start_col = start2 + (N_NODES+1);
  int j = blockIdx.x;
  int tid = threadIdx.x, wv = tid >> 6, lane = tid & 63;
  int clo = start_col[j], chi = start_col[j+1];
  int rlo = start_row[j], rhi = start_row[j+1];
  if (clo < 0) clo = 0; if (chi > E_EDGES) chi = E_EDGES; if (chi < clo) chi = clo;
  if (rlo < 0) rlo = 0; if (rhi > E_EDGES) rhi = E_EDGES; if (rhi < rlo) rhi = rlo;
  int nI = chi - clo, nO = rhi - rlo;
  int nS = half ? nO : nI;
  int nT = half ? nI : nO;
  int slo = half ? rlo : clo;
  int tlo = half ? clo : rlo;
  const int* slist = half ? list_row : list_col;
  const int* tlist = half ? list_col : list_row;
  if (nT == 0) return;
  int isbf = flg[0];

  if (nS <= DEG_CAP && nT <= DEG_CAP){
    if (tid < nS){
      int s = clampi(slist[slo+tid], E_EDGES);
      othS[tid] = clampi(half ? col[s] : row[s], N_NODES);
      eS[tid] = ldv(eattr, s, isbf);
      vS[tid][0]=vecn[s*4+0]; vS[tid][1]=vecn[s*4+1];
      vS[tid][2]=vecn[s*4+2]; vS[tid][3]=vecn[s*4+3];
    }
    if (tid < nT){
      int t = clampi(tlist[tlo+tid], E_EDGES);
      posT[tid] = clampi(pos_col[t], E_EDGES);
      vT[tid][0]=vecn[t*4+0]; vT[tid][1]=vecn[t*4+1];
      vT[tid][2]=vecn[t*4+2]; vT[tid][3]=vecn[t*4+3];
    }
    for (int i = tid; i < DEG_CAP*8; i += 256) ((float*)e64)[i] = 0.f;
    __syncthreads();
    // stage source features: half=0 -> [x[other] | x[j]], half=1 -> [x[j] | x[other]]
    for (int cidx = tid; cidx < nS*64; cidx += 256){
      int si = cidx >> 6, f = cidx & 63;
      int lo_node = half ? j : othS[si];
      int hi_node = half ? othS[si] : j;
      int src = (f < 32) ? (lo_node*C_DIM + f) : (hi_node*C_DIM + f - 32);
      fS[si][f] = f2bf(ldv(x, (size_t)src, isbf));
    }
    // pair bins: cos = -(vec_s . vec_t)/(|s||t|+1e-8), symmetric in (s,t)
    for (int p = tid; p < nS*64; p += 256){
      int si = p >> 6, ti = p & 63;
      if (ti < nT){
        float dot = -(vS[si][0]*vT[ti][0] + vS[si][1]*vT[ti][1] + vS[si][2]*vT[ti][2]);
        float cv = dot / (vS[si][3]*vT[ti][3] + 1e-8f);
        int t = (cv<=cb1)+(cv<=cb2)+(cv<=cb3)+(cv<=-cb3)+(cv<=-cb2)+(cv<=-cb1);
        bins[ti][si] = (unsigned char)t;
        atomicAdd(&e64[ti][t], eS[si]);
      }
    }
    __syncthreads();
    for (int ti = wv; ti < nT; ti += 4){
      float S0=0,S1=0,S2=0,S3=0,S4=0,S5=0,S6=0;
      for (int si = 0; si < nS; ++si){
        int t = bins[ti][si];                 // wave-uniform LDS broadcast
        float val = bf2f(fS[si][lane]);
        switch(t){
          case 0: S0+=val; break; case 1: S1+=val; break; case 2: S2+=val; break;
          case 3: S3+=val; break; case 4: S4+=val; break; case 5: S5+=val; break;
          default: S6+=val; break;
        }
      }
      unsigned short* mrow = msg + (size_t)posT[ti]*KPH;
      mrow[0*65+lane]=f2bf(S0); mrow[1*65+lane]=f2bf(S1); mrow[2*65+lane]=f2bf(S2);
      mrow[3*65+lane]=f2bf(S3); mrow[4*65+lane]=f2bf(S4); mrow[5*65+lane]=f2bf(S5);
      mrow[6*65+lane]=f2bf(S6);
      if (lane < 7)  mrow[lane*65+64] = f2bf(e64[ti][lane]);
      if (lane < 57) mrow[455+lane] = 0;
    }
  } else {
    // degree > cap fallback: all-global (correct, ~never taken for this graph)
    for (int ti = wv; ti < nT; ti += 4){
      int te = clampi(tlist[tlo+ti], E_EDGES);
      float tx=vecn[te*4+0], ty=vecn[te*4+1], tz=vecn[te*4+2], tn=vecn[te*4+3];
      float S0=0,S1=0,S2=0,S3=0,S4=0,S5=0,S6=0,S64v=0;
      for (int si = 0; si < nS; ++si){
        int se = clampi(slist[slo+si], E_EDGES);
        float dot = -(vecn[se*4+0]*tx + vecn[se*4+1]*ty + vecn[se*4+2]*tz);
        float cv = dot / (vecn[se*4+3]*tn + 1e-8f);
        int tv = (cv<=cb1)+(cv<=cb2)+(cv<=cb3)+(cv<=-cb3)+(cv<=-cb2)+(cv<=-cb1);
        int t = __builtin_amdgcn_readfirstlane(tv);
        int oth = clampi(half ? col[se] : row[se], N_NODES);
        int lo_node = half ? j : oth;
        int hi_node = half ? oth : j;
        float val = (lane < 32) ? ldv(x, (size_t)lo_node*C_DIM+lane, isbf)
                                : ldv(x, (size_t)hi_node*C_DIM+lane-32, isbf);
        switch(t){
          case 0: S0+=val; break; case 1: S1+=val; break; case 2: S2+=val; break;
          case 3: S3+=val; break; case 4: S4+=val; break; case 5: S5+=val; break;
          default: S6+=val; break;
        }
        S64v += (lane == t) ? ldv(eattr, se, isbf) : 0.f;
      }
      unsigned short* mrow = msg + (size_t)clampi(pos_col[te], E_EDGES)*KPH;
      mrow[0*65+lane]=f2bf(S0); mrow[1*65+lane]=f2bf(S1); mrow[2*65+lane]=f2bf(S2);
      mrow[3*65+lane]=f2bf(S3); mrow[4*65+lane]=f2bf(S4); mrow[5*65+lane]=f2bf(S5);
      mrow[6*65+lane]=f2bf(S6);
      if (lane < 7)  mrow[lane*65+64] = f2bf(S64v);
      if (lane < 57) mrow[455+lane] = 0;
    }
  }
}

// ---------------- GEMM half: hidden (+)= msg @ Wph^T (+ bias when accum==0) ----------------
__global__ __launch_bounds__(256)
void k_gemm(const unsigned short* __restrict__ msg,
            const unsigned short* __restrict__ Wp,
            const void* __restrict__ bias,
            const int* __restrict__ flg,
            float* __restrict__ hidden, int accum)
{
  __shared__ unsigned short As[MT*BK];
  __shared__ unsigned short Bs[OUT_DIM*BK];
  int tid = threadIdx.x;
  int w = tid >> 6, lane = tid & 63;
  int lrow = lane & 15, q = lane >> 4;
  int m0 = blockIdx.x * MT;

  f32x4 acc[2][8];
  #pragma unroll
  for (int i = 0; i < 2; ++i)
    #pragma unroll
    for (int jn = 0; jn < 8; ++jn) acc[i][jn] = (f32x4)0.f;

  for (int k0 = 0; k0 < KPH; k0 += BK){
    __syncthreads();
    #pragma unroll
    for (int i = 0; i < 4; ++i){
      int idx = tid + i*256;
      int rr = idx >> 3, cc = idx & 7;
      const uint4* gp = (const uint4*)(msg + (size_t)(m0+rr)*KPH + k0 + cc*8);
      *(uint4*)(As + rr*BK + ((cc ^ (rr & 7)) * 8)) = *gp;
      const uint4* gq = (const uint4*)(Wp + (size_t)rr*KPH + k0 + cc*8);
      *(uint4*)(Bs + rr*BK + ((cc ^ (rr & 7)) * 8)) = *gq;
    }
    __syncthreads();
    #pragma unroll
    for (int kk = 0; kk < 2; ++kk){
      int cbase = kk*4 + q;
      int ra0 = w*32 + lrow;
      int ra1 = ra0 + 16;
      short8 a0 = *(const short8*)(As + ra0*BK + ((cbase ^ (ra0 & 7))*8));
      short8 a1 = *(const short8*)(As + ra1*BK + ((cbase ^ (ra1 & 7))*8));
      #pragma unroll
      for (int nf = 0; nf < 8; ++nf){
        int rb = nf*16 + lrow;
        short8 bfr = *(const short8*)(Bs + rb*BK + ((cbase ^ (rb & 7))*8));
        acc[0][nf] = __builtin_amdgcn_mfma_f32_16x16x32_bf16(a0, bfr, acc[0][nf], 0, 0, 0);
        acc[1][nf] = __builtin_amdgcn_mfma_f32_16x16x32_bf16(a1, bfr, acc[1][nf], 0, 0, 0);
      }
    }
  }
  int isbf = flg[0];
  float bvs[8];
  #pragma unroll
  for (int nf = 0; nf < 8; ++nf)
    bvs[nf] = accum ? 0.f : ldv(bias, nf*16 + lrow, isbf);

  #pragma unroll
  for (int mf = 0; mf < 2; ++mf){
    #pragma unroll
    for (int r = 0; r < 4; ++r){
      int m = w*32 + mf*16 + q*4 + r;
      float* hp = hidden + (size_t)(m0+m)*OUT_DIM;
      #pragma unroll
      for (int nf = 0; nf < 8; ++nf){
        int o = nf*16 + lrow;
        float v = acc[mf][nf][r] + bvs[nf];
        if (accum) hp[o] += v; else hp[o] = v;
      }
    }
  }
}

// ---------------- node gather: contiguous col-sorted ranges ----------------
__global__ void k_gather(const float* __restrict__ hidden,
                         const int* __restrict__ start2,
                         void* __restrict__ outp, const int* __restrict__ flg)
{
  const int* start_col = start2 + (N_NODES+1);
  int n = blockIdx.x;
  int o = threadIdx.x;
  int lo = start_col[n], hi = start_col[n+1];
  if (lo < 0) lo = 0; if (hi > E_EDGES) hi = E_EDGES; if (hi < lo) hi = lo;
  float s = 0.f;
  for (int i = lo; i < hi; ++i)
    s += hidden[(size_t)i*OUT_DIM + o];
  if (flg[0]) ((unsigned short*)outp)[(size_t)n*OUT_DIM + o] = f2bf(s);
  else        ((float*)outp)[(size_t)n*OUT_DIM + o] = s;
}

extern "C" void kernel_launch(void* const* d_in, const int* in_sizes, int n_in,
                              void* d_out, int out_size, void* d_ws, size_t ws_size,
                              hipStream_t stream)
{
  const void* x     = d_in[0];
  const void* eattr = d_in[1];
  const void* pos   = d_in[2];
  const void* W     = d_in[3];
  const void* bmsg  = d_in[4];
  const int* eidx = (const int*)d_in[5];
  const int* row = eidx;
  const int* col = eidx + E_EDGES;

  char* ws = (char*)d_ws;
  size_t off = 0;
  auto alloc = [&](size_t b){ size_t o = off; off += (b + 255) & ~(size_t)255; return o; };

  int* dflag     = (int*)(ws + alloc(256));
  float* vecn    = (float*)(ws + alloc((size_t)E_EDGES*16));
  int* cnt       = (int*)(ws + alloc((size_t)2*N_NODES*4));
  int* start2    = (int*)(ws + alloc((size_t)2*(N_NODES+1)*4));
  int* fill2     = (int*)(ws + alloc((size_t)2*N_NODES*4));
  int* segsum    = (int*)(ws + alloc((size_t)2*NSEG*4));
  int* list_row  = (int*)(ws + alloc((size_t)E_EDGES*4));
  int* list_col  = (int*)(ws + alloc((size_t)E_EDGES*4));
  int* pos_col   = (int*)(ws + alloc((size_t)E_EDGES*4));
  unsigned short* Wp  = (unsigned short*)(ws + alloc((size_t)2*OUT_DIM*KPH*2));
  float* hidden  = (float*)(ws + alloc((size_t)E_EDGES*OUT_DIM*4));
  unsigned short* msg = (unsigned short*)(ws + alloc((size_t)E_EDGES*KPH*2));
  (void)off; // total ~251 MB; ws_size reconstructed as 256 MiB (round-2 WRITE_SIZE match)

  unsigned short* Wp_in  = Wp;
  unsigned short* Wp_out = Wp + (size_t)OUT_DIM*KPH;

  k_sniff<<<1, 256, 0, stream>>>(x, dflag);
  k_zero<<<(2*N_NODES+255)/256, 256, 0, stream>>>(cnt, 2*N_NODES);
  k_build<<<(E_EDGES+255)/256, 256, 0, stream>>>(pos, row, col, vecn, cnt, dflag);
  k_scan1<<<2*NSEG, SEG, 0, stream>>>(cnt, start2, segsum);
  k_scan2<<<1, 64, 0, stream>>>(segsum);
  k_scan3<<<2*NSEG, SEG, 0, stream>>>(start2, fill2, segsum);
  k_scatter<<<(E_EDGES+255)/256, 256, 0, stream>>>(row, col, fill2,
                                                   list_row, list_col, pos_col);
  k_packw<<<(2*OUT_DIM*KPH+255)/256, 256, 0, stream>>>(W, Wp, dflag);

  // phase 1: in-halves
  k_msg_node<<<N_NODES, 256, 0, stream>>>(x, eattr, vecn, row, col, start2,
                                          list_row, list_col, pos_col, msg, dflag, 0);
  k_gemm<<<E_EDGES/MT, 256, 0, stream>>>(msg, Wp_in, bmsg, dflag, hidden, 0);
  // phase 2: out-halves (reuse msg buffer; stream-ordered after gemm1)
  k_msg_node<<<N_NODES, 256, 0, stream>>>(x, eattr, vecn, row, col, start2,
                                          list_row, list_col, pos_col, msg, dflag, 1);
  k_gemm<<<E_EDGES/MT, 256, 0, stream>>>(msg, Wp_out, bmsg, dflag, hidden, 1);

  k_gather<<<N_NODES, OUT_DIM, 0, stream>>>(hidden, start2, d_out, dflag);
}